// Round 6
// baseline (69.361 us; speedup 1.0000x reference)
//
#include <hip/hip_runtime.h>
#include <math.h>

// Problem constants (match reference)
constexpr int   B_    = 2048;
constexpr int   L_    = 8192;
constexpr int   G_    = 256;
constexpr float BETA_ = 0.01f;
constexpr float BIG_  = 1024.0f;   // linear y-flag encoding (validated in prior rounds)

// GEMM decomposition: C[B_ x G_] = A[B_ x L_] * M[L_ x G_], M one-hot per row.
constexpr int   BM    = 32;        // rows per block
constexpr int   NRT   = B_ / BM;   // 64 row-tiles
constexpr int   NKC   = 8;         // split-K chunks
constexpr int   KC    = L_ / NKC;  // 1024 K per chunk
constexpr int   NKST  = KC / 64;   // 16 K-steps of 64

typedef short  bf16x8 __attribute__((ext_vector_type(8)));
typedef float  f32x4  __attribute__((ext_vector_type(4)));

// log(sigmoid(-x)) = -softplus(x) = -(max(x,0) + log(1 + exp(-|x|)))
__device__ __forceinline__ float log_sigmoid_neg(float x) {
    return -(fmaxf(x, 0.0f) + __logf(1.0f + __expf(-fabsf(x))));
}

// f32 -> bf16, round-to-nearest-even
__device__ __forceinline__ unsigned int f2bf(float f) {
    unsigned int u = __float_as_uint(f);
    return (u + 0x7FFFu + ((u >> 16) & 1u)) >> 16;
}

// ---------------------------------------------------------------------------
// Prep: M_T[g][l] = bf16(1.0) where group_ids[l]==g, else 0 (buffer pre-zeroed
// by hipMemsetAsync). 4 MB, L2-resident for the whole main pass.
// ---------------------------------------------------------------------------
extern "C" __global__ __launch_bounds__(1024)
void build_m_kernel(const int* __restrict__ group_ids,
                    unsigned short* __restrict__ Mt)   // [G_][L_] bf16
{
    const int l = blockIdx.x * 1024 + threadIdx.x;     // 8 blocks
    Mt[(size_t)group_ids[l] * L_ + l] = 0x3F80;        // bf16 1.0
}

// ---------------------------------------------------------------------------
// Main: 512 blocks (64 row-tiles x 8 K-chunks) x 256 threads (4 waves).
// Per K-step (BK=64):
//   stage: each thread loads 8 consecutive logits/y of one row (coalesced),
//          computes logsig, packs bf16x8, ds_write_b128 into XOR-swizzled
//          A-tiles (chunk ^ row&7 -> conflict-free b128 frag reads).
//   mfma : wave w owns cols [64w,64w+64): 2 m-frags x 4 n-frags x 2 gemms.
//          B-frags = direct 16B global loads from M_T (L2-hot, no LDS).
// Epilogue: enc = acc_x + 1024*acc_y (linear BIG encoding), plain stores to
// split-K slab partial[kc] — no atomics, every slot written exactly once.
// ---------------------------------------------------------------------------
extern "C" __global__ __launch_bounds__(256, 2)
void meta_gemm_kernel(const float* __restrict__ logits,
                      const int*   __restrict__ true_y,
                      const unsigned short* __restrict__ Mt,   // [G_][L_] bf16
                      float*       __restrict__ partial)       // [NKC][B_][G_]
{
    __shared__ int4 sAx4[BM * 8];    // [row][slot] 16B units, 4 KB
    __shared__ int4 sAy4[BM * 8];
    unsigned short* sAx = (unsigned short*)sAx4;
    unsigned short* sAy = (unsigned short*)sAy4;

    const int t    = threadIdx.x;            // 0..255
    const int kc   = blockIdx.x & (NKC - 1);
    const int rt   = blockIdx.x >> 3;        // 0..63
    const int w    = t >> 6;                 // wave 0..3
    const int lane = t & 63;
    const int mrow = lane & 15;              // non-K index within fragment
    const int kgrp = lane >> 4;              // K-block 0..3

    // staging role: thread t -> (row srow, global k-chunk schunk of 8)
    const int srow   = t >> 3;               // 0..31
    const int schunk = t & 7;                // 0..7
    const int sslot  = schunk ^ (srow & 7);  // XOR-swizzled 16B slot

    const float* lgrow = logits + (size_t)(rt * BM + srow) * L_ + kc * KC + schunk * 8;
    const int*   tyrow = true_y + (size_t)(rt * BM + srow) * L_ + kc * KC + schunk * 8;

    f32x4 accx[2][4], accy[2][4];
    #pragma unroll
    for (int mf = 0; mf < 2; ++mf)
        #pragma unroll
        for (int nf = 0; nf < 4; ++nf) {
            accx[mf][nf] = (f32x4){0.f, 0.f, 0.f, 0.f};
            accy[mf][nf] = (f32x4){0.f, 0.f, 0.f, 0.f};
        }

    for (int kst = 0; kst < NKST; ++kst) {
        // ---- stage A_x / A_y (each element touched exactly once) ----
        const float4 xa = *(const float4*)(lgrow + kst * 64);
        const float4 xb = *(const float4*)(lgrow + kst * 64 + 4);
        const int4   ya = *(const int4*)(tyrow + kst * 64);
        const int4   yb = *(const int4*)(tyrow + kst * 64 + 4);

        int4 wx, wy;
        wx.x = (int)(f2bf(log_sigmoid_neg(xa.x)) | (f2bf(log_sigmoid_neg(xa.y)) << 16));
        wx.y = (int)(f2bf(log_sigmoid_neg(xa.z)) | (f2bf(log_sigmoid_neg(xa.w)) << 16));
        wx.z = (int)(f2bf(log_sigmoid_neg(xb.x)) | (f2bf(log_sigmoid_neg(xb.y)) << 16));
        wx.w = (int)(f2bf(log_sigmoid_neg(xb.z)) | (f2bf(log_sigmoid_neg(xb.w)) << 16));
        wy.x = (ya.x ? 0x3F80 : 0) | ((ya.y ? 0x3F80 : 0) << 16);
        wy.y = (ya.z ? 0x3F80 : 0) | ((ya.w ? 0x3F80 : 0) << 16);
        wy.z = (yb.x ? 0x3F80 : 0) | ((yb.y ? 0x3F80 : 0) << 16);
        wy.w = (yb.z ? 0x3F80 : 0) | ((yb.w ? 0x3F80 : 0) << 16);

        sAx4[srow * 8 + sslot] = wx;
        sAy4[srow * 8 + sslot] = wy;
        __syncthreads();

        // ---- MFMA phase ----
        #pragma unroll
        for (int ks = 0; ks < 2; ++ks) {
            const int c = ks * 4 + kgrp;     // global 16B chunk within the 64-K step

            bf16x8 ax[2], ay[2];
            #pragma unroll
            for (int mf = 0; mf < 2; ++mf) {
                const int m    = mf * 16 + mrow;
                const int slot = c ^ (m & 7);
                ax[mf] = *(const bf16x8*)&sAx[m * 64 + slot * 8];
                ay[mf] = *(const bf16x8*)&sAy[m * 64 + slot * 8];
            }

            #pragma unroll
            for (int nf = 0; nf < 4; ++nf) {
                const int n = w * 64 + nf * 16 + mrow;
                const bf16x8 bq = *(const bf16x8*)(
                    Mt + (size_t)n * L_ + kc * KC + kst * 64 + ks * 32 + kgrp * 8);
                #pragma unroll
                for (int mf = 0; mf < 2; ++mf) {
                    accx[mf][nf] = __builtin_amdgcn_mfma_f32_16x16x32_bf16(
                                       ax[mf], bq, accx[mf][nf], 0, 0, 0);
                    accy[mf][nf] = __builtin_amdgcn_mfma_f32_16x16x32_bf16(
                                       ay[mf], bq, accy[mf][nf], 0, 0, 0);
                }
            }
        }
        __syncthreads();
    }

    // ---- epilogue: linear BIG encoding, plain coalesced-ish stores ----
    // C/D layout (m89 verified): col = lane&15, row = (lane>>4)*4 + reg
    #pragma unroll
    for (int mf = 0; mf < 2; ++mf)
        #pragma unroll
        for (int nf = 0; nf < 4; ++nf) {
            const int col = w * 64 + nf * 16 + mrow;
            float* pb = partial + ((size_t)kc * B_ + rt * BM + mf * 16 + kgrp * 4) * G_ + col;
            #pragma unroll
            for (int r = 0; r < 4; ++r)
                pb[(size_t)r * G_] = accx[mf][nf][r] + BIG_ * accy[mf][nf][r];
        }
}

// ---------------------------------------------------------------------------
// Finalize: sum 8 split-K slabs, decode BIG encoding, BCE terms, reduce.
// ---------------------------------------------------------------------------
extern "C" __global__ __launch_bounds__(1024)
void finalize_kernel(const float* __restrict__ partial,
                     float* __restrict__ out)
{
    __shared__ float s_part[16];

    const int t   = threadIdx.x;
    const int idx = blockIdx.x * 1024 + t;    // 512 blocks x 1024 = 524288

    float enc = 0.0f;
    #pragma unroll
    for (int s = 0; s < NKC; ++s)
        enc += partial[(size_t)s * B_ * G_ + idx];

    const int   k  = __float2int_rn(enc * (1.0f / BIG_));   // # true labels (exact)
    const float gl = enc - BIG_ * (float)k;                 // sum log(1-sig)

    float term;
    if (k != 0) {
        term = fmaxf(gl, -100.0f);                    // meta_y = 1: log(p)
    } else {
        // empty/all-false group: gl<=0; gl==0 -> log1p(-1) = -inf -> clamp
        term = fmaxf(log1pf(-__expf(gl)), -100.0f);   // meta_y = 0
    }

    #pragma unroll
    for (int off = 32; off > 0; off >>= 1)
        term += __shfl_down(term, off, 64);
    if ((t & 63) == 0) s_part[t >> 6] = term;
    __syncthreads();

    if (t == 0) {
        float s = 0.0f;
        #pragma unroll
        for (int wv = 0; wv < 16; ++wv) s += s_part[wv];
        atomicAdd(out, s * (-BETA_ / ((float)B_ * (float)G_)));
    }
}

extern "C" void kernel_launch(void* const* d_in, const int* in_sizes, int n_in,
                              void* d_out, int out_size, void* d_ws, size_t ws_size,
                              hipStream_t stream) {
    const float* logits    = (const float*)d_in[0];
    const int*   true_y    = (const int*)d_in[1];
    const int*   group_ids = (const int*)d_in[2];
    float*       out       = (float*)d_out;

    // workspace: [0, 4MB) M_T bf16 [256][8192]; [4MB, 20MB) partial [8][2048][256] f32
    unsigned short* Mt      = (unsigned short*)d_ws;
    float*          partial = (float*)((char*)d_ws + (size_t)G_ * L_ * 2);

    hipMemsetAsync(Mt, 0, (size_t)G_ * L_ * 2, stream);   // 4 MB
    hipMemsetAsync(out, 0, sizeof(float), stream);

    build_m_kernel<<<L_ / 1024, 1024, 0, stream>>>(group_ids, Mt);
    meta_gemm_kernel<<<NRT * NKC, 256, 0, stream>>>(logits, true_y, Mt, partial);
    finalize_kernel<<<(B_ * G_) / 1024, 1024, 0, stream>>>(partial, out);
}

// Round 7
// 61.140 us; speedup vs baseline: 1.1345x; 1.1345x over previous
//
#include <hip/hip_runtime.h>
#include <math.h>

// Problem constants (match reference)
constexpr int   B_    = 2048;
constexpr int   L_    = 8192;
constexpr int   G_    = 256;
constexpr float BETA_ = 0.01f;
constexpr float BIG_  = 1024.0f;   // linear y-flag encoding (validated R0-R6)

// GEMM decomposition: C[B_ x G_] = A[B_ x L_] * M[L_ x G_], M one-hot per row.
// M is never materialized: B-fragments built in registers from gid bytes.
constexpr int   BM    = 32;        // rows per block
constexpr int   NRT   = B_ / BM;   // 64 row-tiles
constexpr int   NKC   = 8;         // split-K chunks
constexpr int   KC    = L_ / NKC;  // 1024 K per chunk
constexpr int   NKST  = KC / 64;   // 16 K-steps of 64

typedef short  bf16x8 __attribute__((ext_vector_type(8)));
typedef float  f32x4  __attribute__((ext_vector_type(4)));

// log(sigmoid(-x)) = -softplus(x) = -(max(x,0) + log(1 + exp(-|x|)))
__device__ __forceinline__ float log_sigmoid_neg(float x) {
    return -(fmaxf(x, 0.0f) + __logf(1.0f + __expf(-fabsf(x))));
}

// f32 -> bf16, round-to-nearest-even
__device__ __forceinline__ unsigned int f2bf(float f) {
    unsigned int u = __float_as_uint(f);
    return (u + 0x7FFFu + ((u >> 16) & 1u)) >> 16;
}

// Direct global->LDS 16B/lane DMA: no dest VGPR, vmcnt-counted, issue depth
// guaranteed (R4/R5 verified). LDS dest = wave-uniform base + lane*16.
#define GLOAD_LDS16(gp, lp)                                               \
    __builtin_amdgcn_global_load_lds(                                     \
        (const __attribute__((address_space(1))) unsigned int*)(gp),      \
        (__attribute__((address_space(3))) unsigned int*)(lp), 16, 0, 0)

#define WAITV(n) asm volatile("s_waitcnt vmcnt(" #n ")" ::: "memory")
#define LDSBAR() do { asm volatile("s_waitcnt lgkmcnt(0)" ::: "memory"); \
                      __builtin_amdgcn_s_barrier(); } while (0)

// ---------------------------------------------------------------------------
// Prep: pack group_ids (0..255) into u8 -> 8 KB, L2-hot for all blocks.
// ---------------------------------------------------------------------------
extern "C" __global__ __launch_bounds__(1024)
void pack_gid_kernel(const int* __restrict__ group_ids,
                     unsigned int* __restrict__ gid8)
{
    const int j = blockIdx.x * 1024 + threadIdx.x;        // 2 blocks -> 2048 u32
    const int4 g = ((const int4*)group_ids)[j];
    gid8[j] = (unsigned)(g.x & 255) | ((unsigned)(g.y & 255) << 8) |
              ((unsigned)(g.z & 255) << 16) | ((unsigned)(g.w & 255) << 24);
}

// ---------------------------------------------------------------------------
// Main: 512 blocks (64 rt x 8 kc) x 256 threads (4 waves).
// Per K-step (64):
//   y int4x2 -> regs (issued before WAITV fence: [y x2][WAITV(2)][stage x2]
//     => compiler waits y at vmcnt(2); next-step logits stay in flight)
//   logits: global_load_lds double-buffer, 2 ops/wave/iter, 1 step ahead
//   thread re-reads its 8 raw f32 (wave-local region: no barrier needed),
//     computes logsig once, packs bf16, ds_writes swizzled A-tiles (x and y)
//   MFMA phase: A-frags from LDS (2-way max aliasing), B-frags BUILT IN
//     REGISTERS from gid bytes (s_gid, 1 KB LDS) -- no Mt, no L3 chain.
// Epilogue: enc = acc_x + 1024*acc_y, plain stores to split-K slab (R6 layout,
// HW-verified). Every partial slot written exactly once -> no memset.
// ---------------------------------------------------------------------------
extern "C" __global__ __launch_bounds__(256, 2)
void meta_gemm_kernel(const float* __restrict__ logits,
                      const int*   __restrict__ true_y,
                      const unsigned int* __restrict__ gid8,
                      float*       __restrict__ partial)    // [NKC][B_][G_]
{
    __shared__ float        raw_lg[2][BM][64];   // 16 KB raw logits dbuf
    __shared__ int4         sAx4[BM * 8];        // 4 KB bf16 A_x tile (swizzled)
    __shared__ int4         sAy4[BM * 8];        // 4 KB bf16 A_y tile (swizzled)
    __shared__ unsigned int s_gid[KC / 4];       // 1 KB gid bytes for this kc

    const int t    = threadIdx.x;                // 0..255
    const int kc   = blockIdx.x & (NKC - 1);
    const int rt   = blockIdx.x >> 3;            // 0..63
    const int w    = t >> 6;                     // wave 0..3
    const int lane = t & 63;
    const int mrow = lane & 15;                  // M/N index within fragment
    const int kgrp = lane >> 4;                  // K-group 0..3
    const int srow = t >> 3;                     // staging row 0..31
    const int schunk = t & 7;                    // staging 8-elem chunk 0..7
    const int sslot  = schunk ^ (srow & 7);      // XOR-swizzled 16B slot

    // ---- stage gid bytes for this K-chunk (1 KB, L2-hot) ----
    s_gid[t] = gid8[kc * (KC / 4) + t];

    // ---- per-lane staging geometry ----
    const int    g_row   = 8 * w + (lane >> 4);            // +4j per op
    const int    g_col   = (lane & 15) * 4;
    const float* lg_base = logits + (size_t)(rt * BM) * L_ + kc * KC;
    const int*   ty_base = true_y + (size_t)(rt * BM + srow) * L_ + kc * KC + schunk * 8;

    // ---- prologue: stage k-step 0 ----
    #pragma unroll
    for (int j = 0; j < 2; ++j)
        GLOAD_LDS16(lg_base + (size_t)(g_row + 4 * j) * L_ + g_col,
                    &raw_lg[0][8 * w + 4 * j][0]);

    f32x4 accx[2][4], accy[2][4];
    #pragma unroll
    for (int mf = 0; mf < 2; ++mf)
        #pragma unroll
        for (int nf = 0; nf < 4; ++nf) {
            accx[mf][nf] = (f32x4){0.f, 0.f, 0.f, 0.f};
            accy[mf][nf] = (f32x4){0.f, 0.f, 0.f, 0.f};
        }

    for (int kst = 0; kst < NKST; ++kst) {
        const int cur = kst & 1;

        // y loads BEFORE the WAITV fence (asm memory clobber pins the order)
        const int4 ya = *(const int4*)(ty_base + kst * 64);
        const int4 yb = *(const int4*)(ty_base + kst * 64 + 4);

        WAITV(2);   // drains this step's logit stage; leaves y (2 newest) flying

        if (kst + 1 < NKST) {
            #pragma unroll
            for (int j = 0; j < 2; ++j)
                GLOAD_LDS16(lg_base + (size_t)(g_row + 4 * j) * L_ + (kst + 1) * 64 + g_col,
                            &raw_lg[cur ^ 1][8 * w + 4 * j][0]);
        }

        // ---- raw re-read (own wave's staged region) + encode + tile write ----
        const float4 xa = *(const float4*)&raw_lg[cur][srow][schunk * 8];
        const float4 xb = *(const float4*)&raw_lg[cur][srow][schunk * 8 + 4];

        int4 wx, wy;
        wx.x = (int)(f2bf(log_sigmoid_neg(xa.x)) | (f2bf(log_sigmoid_neg(xa.y)) << 16));
        wx.y = (int)(f2bf(log_sigmoid_neg(xa.z)) | (f2bf(log_sigmoid_neg(xa.w)) << 16));
        wx.z = (int)(f2bf(log_sigmoid_neg(xb.x)) | (f2bf(log_sigmoid_neg(xb.y)) << 16));
        wx.w = (int)(f2bf(log_sigmoid_neg(xb.z)) | (f2bf(log_sigmoid_neg(xb.w)) << 16));
        wy.x = (ya.x ? 0x3F80 : 0) | ((ya.y ? 0x3F80 : 0) << 16);
        wy.y = (ya.z ? 0x3F80 : 0) | ((ya.w ? 0x3F80 : 0) << 16);
        wy.z = (yb.x ? 0x3F80 : 0) | ((yb.y ? 0x3F80 : 0) << 16);
        wy.w = (yb.z ? 0x3F80 : 0) | ((yb.w ? 0x3F80 : 0) << 16);

        sAx4[srow * 8 + sslot] = wx;
        sAy4[srow * 8 + sslot] = wy;
        LDSBAR();                     // A-tiles (and, on iter 0, s_gid) visible

        // ---- MFMA phase: register-built one-hot B ----
        #pragma unroll
        for (int ks = 0; ks < 2; ++ks) {
            const unsigned g0 = s_gid[kst * 16 + ks * 8 + kgrp * 2];
            const unsigned g1 = s_gid[kst * 16 + ks * 8 + kgrp * 2 + 1];

            bf16x8 ax[2], ay[2];
            #pragma unroll
            for (int mf = 0; mf < 2; ++mf) {
                const int m    = mf * 16 + mrow;
                const int slot = (ks * 4 + kgrp) ^ (m & 7);
                ax[mf] = *(const bf16x8*)((const unsigned short*)sAx4 + m * 64 + slot * 8);
                ay[mf] = *(const bf16x8*)((const unsigned short*)sAy4 + m * 64 + slot * 8);
            }

            #pragma unroll
            for (int nf = 0; nf < 4; ++nf) {
                const unsigned n = (unsigned)(w * 64 + nf * 16 + mrow);
                bf16x8 bq;
                #pragma unroll
                for (int j = 0; j < 4; ++j)
                    bq[j] = (short)((((g0 >> (8 * j)) & 255u) == n) ? 0x3F80 : 0);
                #pragma unroll
                for (int j = 0; j < 4; ++j)
                    bq[4 + j] = (short)((((g1 >> (8 * j)) & 255u) == n) ? 0x3F80 : 0);

                #pragma unroll
                for (int mf = 0; mf < 2; ++mf) {
                    accx[mf][nf] = __builtin_amdgcn_mfma_f32_16x16x32_bf16(
                                       ax[mf], bq, accx[mf][nf], 0, 0, 0);
                    accy[mf][nf] = __builtin_amdgcn_mfma_f32_16x16x32_bf16(
                                       ay[mf], bq, accy[mf][nf], 0, 0, 0);
                }
            }
        }
        LDSBAR();                     // frag reads done; next iter may overwrite
    }

    // ---- epilogue: linear BIG encoding, plain stores (R6 HW-verified map) ----
    // C/D layout: col = lane&15, row = (lane>>4)*4 + reg
    #pragma unroll
    for (int mf = 0; mf < 2; ++mf)
        #pragma unroll
        for (int nf = 0; nf < 4; ++nf) {
            const int col = w * 64 + nf * 16 + mrow;
            float* pb = partial + ((size_t)kc * B_ + rt * BM + mf * 16 + kgrp * 4) * G_ + col;
            #pragma unroll
            for (int r = 0; r < 4; ++r)
                pb[(size_t)r * G_] = accx[mf][nf][r] + BIG_ * accy[mf][nf][r];
        }
}

// ---------------------------------------------------------------------------
// Finalize: sum 8 split-K slabs, decode BIG encoding, BCE terms, reduce.
// ---------------------------------------------------------------------------
extern "C" __global__ __launch_bounds__(1024)
void finalize_kernel(const float* __restrict__ partial,
                     float* __restrict__ out)
{
    __shared__ float s_part[16];

    const int t   = threadIdx.x;
    const int idx = blockIdx.x * 1024 + t;    // 512 blocks x 1024 = 524288

    float enc = 0.0f;
    #pragma unroll
    for (int s = 0; s < NKC; ++s)
        enc += partial[(size_t)s * B_ * G_ + idx];

    const int   k  = __float2int_rn(enc * (1.0f / BIG_));   // # true labels (exact)
    const float gl = enc - BIG_ * (float)k;                 // sum log(1-sig)

    float term;
    if (k != 0) {
        term = fmaxf(gl, -100.0f);                    // meta_y = 1: log(p)
    } else {
        // empty/all-false group: gl<=0; gl==0 -> log1p(-1) = -inf -> clamp
        term = fmaxf(log1pf(-__expf(gl)), -100.0f);   // meta_y = 0
    }

    #pragma unroll
    for (int off = 32; off > 0; off >>= 1)
        term += __shfl_down(term, off, 64);
    if ((t & 63) == 0) s_part[t >> 6] = term;
    __syncthreads();

    if (t == 0) {
        float s = 0.0f;
        #pragma unroll
        for (int wv = 0; wv < 16; ++wv) s += s_part[wv];
        atomicAdd(out, s * (-BETA_ / ((float)B_ * (float)G_)));
    }
}

extern "C" void kernel_launch(void* const* d_in, const int* in_sizes, int n_in,
                              void* d_out, int out_size, void* d_ws, size_t ws_size,
                              hipStream_t stream) {
    const float* logits    = (const float*)d_in[0];
    const int*   true_y    = (const int*)d_in[1];
    const int*   group_ids = (const int*)d_in[2];
    float*       out       = (float*)d_out;

    // workspace: [0, 16MB) partial [8][2048][256] f32; [16MB, +8KB) gid8 u8
    float*        partial = (float*)d_ws;
    unsigned int* gid8    = (unsigned int*)((char*)d_ws + (size_t)NKC * B_ * G_ * 4);

    hipMemsetAsync(out, 0, sizeof(float), stream);

    pack_gid_kernel<<<2, 1024, 0, stream>>>(group_ids, gid8);
    meta_gemm_kernel<<<NRT * NKC, 256, 0, stream>>>(logits, true_y, gid8, partial);
    finalize_kernel<<<(B_ * G_) / 1024, 1024, 0, stream>>>(partial, out);
}